// Round 17
// baseline (421.376 us; speedup 1.0000x reference)
//
#include <hip/hip_runtime.h>
#include <cstdint>
#include <cstddef>

// PPmodel_all_preprocess — MI355X, round 17: bn3 fold fused into k_smax via
// LDS tile staging (kills the 128MB k_foldf round-trip).
//
// Round-16: coalesced frag loads confirmed the TA theory (k_smax 137->110,
// FETCH const). Tail is now 73% of total; largest item is k_foldf (128MB
// HBM r/w + launch ~40us). All 4 k_smax waves read the SAME 16KB tile, so:
// stage it to LDS once per block, folding bn3 (sc/sh from padded st3) during
// the stage — same math/rounding as k_foldf; waves read frag rows from LDS
// conflict-free. Register pressure flat (round-14's reg-fold spill avoided
// by going through LDS). 22KB LDS, occupancy unchanged.
//
// Workspace: y3F(raw) | y1 | y2 | pooled(alias) | counts | stats(x16) |
//   offs | cur | bsum | pidf | send | skey | inv | W3F | W4F | WcF | W2F | scsh

#define P_TOT  131072
#define HWSZ   65536
#define WGRID  256
#define S_TOT  131072
#define EPS    1e-5f
#define CNTF   131072.0f

#define OFF_Y3    0ull
#define OFF_Y1    67108864ull
#define OFF_Y2    100663296ull
#define OFF_POOL  67108864ull
#define OFF_CNT   201326592ull
#define OFF_ST    201850880ull
#define OFF_OFFS  201916416ull
#define OFF_CUR   202440704ull
#define OFF_BSUM  202964992ull
#define OFF_PIDF  202969088ull
#define OFF_SEND  203493376ull
#define OFF_SKEY  204017664ull
#define OFF_INV   204541952ull
#define OFF_W3F   205066240ull
#define OFF_W4F   205131776ull
#define OFF_WCF   205393920ull
#define OFF_W2F   205426688ull
#define OFF_SCSH  205443072ull

typedef __attribute__((ext_vector_type(8)))  short bf16x8;
typedef __attribute__((ext_vector_type(16))) float f32x16;

// ---- bf16 helpers (manual, RNE) ----
__device__ __forceinline__ unsigned f2bf(float f) {
    unsigned u = __float_as_uint(f);
    return (u + 0x7FFFu + ((u >> 16) & 1u)) >> 16;   // RNE, finite inputs
}
__device__ __forceinline__ float bf2f(unsigned h) {
    return __uint_as_float(h << 16);
}

// ---- zero-fill (graph-capture-safe memset replacement) ----
__global__ __launch_bounds__(256) void k_zero(uint4* __restrict__ p, int n_u4) {
    int i = blockIdx.x * blockDim.x + threadIdx.x;
    if (i < n_u4) p[i] = make_uint4(0u, 0u, 0u, 0u);
}

// ---- Prep: W2/W3/W4/Wc -> bf16 frag layout (32x32x16 operand) ----
__global__ __launch_bounds__(256) void k_prepw(
    const float* __restrict__ W2, const float* __restrict__ W3,
    const float* __restrict__ W4, const float* __restrict__ Wc,
    uint4* __restrict__ W2F, uint4* __restrict__ W3F,
    uint4* __restrict__ W4F, uint4* __restrict__ WcF)
{
    int gw = (blockIdx.x * 256 + threadIdx.x) >> 6;
    int l = threadIdx.x & 63;
    const float* W; uint4* dst; int M, mt, ks, fi;
    if (gw < 64)       { fi = gw;       W = W3; dst = W3F; M = 256; mt = fi >> 3; ks = fi & 7;  }
    else if (gw < 320) { fi = gw - 64;  W = W4; dst = W4F; M = 512; mt = fi >> 4; ks = fi & 15; }
    else if (gw < 352) { fi = gw - 320; W = Wc; dst = WcF; M = 32;  mt = 0;      ks = fi;      }
    else               { fi = gw - 352; W = W2; dst = W2F; M = 128; mt = fi >> 2; ks = fi & 3;  }
    int m = mt * 32 + (l & 31);
    int k0 = ks * 16 + (l >> 5) * 8;
    unsigned p[4];
    #pragma unroll
    for (int jj = 0; jj < 4; ++jj) {
        unsigned lo = f2bf(W[(size_t)(k0 + 2*jj)     * M + m]);
        unsigned hi = f2bf(W[(size_t)(k0 + 2*jj + 1) * M + m]);
        p[jj] = lo | (hi << 16);
    }
    dst[(size_t)fi * 64 + l] = make_uint4(p[0], p[1], p[2], p[3]);
}

// ---- bn fold coefficients: sc[c] = rs*g, sh[c] = b - mu*sc ----
__global__ __launch_bounds__(256) void k_bnprep(
    const float* __restrict__ st, const float* __restrict__ g,
    const float* __restrict__ b, float* __restrict__ sc,
    float* __restrict__ sh, int nch)
{
    int c = blockIdx.x * 256 + threadIdx.x;
    if (c >= nch) return;
    float mu = st[c * 16] * (1.0f / CNTF);
    float var = st[(nch + c) * 16] * (1.0f / CNTF) - mu * mu;
    float rs = rsqrtf(var + EPS);
    float s = rs * g[c];
    sc[c] = s;
    sh[c] = b[c] - mu * s;
}

// ---- In-place fold (row layout): y = bf16(relu(y*sc+sh)), nch pow2 ----
__global__ __launch_bounds__(256) void k_fold(
    unsigned short* __restrict__ y, const float* __restrict__ sc,
    const float* __restrict__ sh, int nch, int n_u4)
{
    int i = blockIdx.x * 256 + threadIdx.x;
    if (i >= n_u4) return;
    int ch0 = (i * 8) & (nch - 1);
    float4 s0 = *(const float4*)(sc + ch0), s1 = *(const float4*)(sc + ch0 + 4);
    float4 h0 = *(const float4*)(sh + ch0), h1 = *(const float4*)(sh + ch0 + 4);
    float scv[8] = {s0.x,s0.y,s0.z,s0.w,s1.x,s1.y,s1.z,s1.w};
    float shv[8] = {h0.x,h0.y,h0.z,h0.w,h1.x,h1.y,h1.z,h1.w};
    uint4 e = ((const uint4*)y)[i];
    unsigned eu[4] = {e.x, e.y, e.z, e.w};
    unsigned ou[4];
    #pragma unroll
    for (int jj = 0; jj < 4; ++jj) {
        float x0 = fmaxf(fmaf(bf2f(eu[jj] & 0xFFFFu), scv[2*jj],   shv[2*jj]),   0.f);
        float x1 = fmaxf(fmaf(bf2f(eu[jj] >> 16),     scv[2*jj+1], shv[2*jj+1]), 0.f);
        ou[jj] = f2bf(x0) | (f2bf(x1) << 16);
    }
    ((uint4*)y)[i] = make_uint4(ou[0], ou[1], ou[2], ou[3]);
}

// ---- Kernel 1: bn0 raw stats (block-reduced) + per-voxel point counts ----
__global__ __launch_bounds__(256) void k_stats0(
    const float* __restrict__ pt, const int* __restrict__ xy,
    float* __restrict__ st0, unsigned* __restrict__ counts)
{
    __shared__ float part[4][16];
    const int tid = threadIdx.x;
    const int p = blockIdx.x * 256 + tid;
    const float4* f4 = (const float4*)(pt + (size_t)p * 8);
    float4 a = f4[0], b = f4[1];
    float v[8] = {a.x,a.y,a.z,a.w,b.x,b.y,b.z,b.w};
    int key = (p >> 16) * HWSZ + xy[2*p] * WGRID + xy[2*p + 1];
    atomicAdd(&counts[key], 1u);
    float s[8], q[8];
    #pragma unroll
    for (int k = 0; k < 8; ++k) { s[k] = v[k]; q[k] = v[k]*v[k]; }
    #pragma unroll
    for (int k = 0; k < 8; ++k) {
        #pragma unroll
        for (int off = 32; off > 0; off >>= 1) {
            s[k] += __shfl_down(s[k], off);
            q[k] += __shfl_down(q[k], off);
        }
    }
    if ((tid & 63) == 0) {
        int w = tid >> 6;
        #pragma unroll
        for (int k = 0; k < 8; ++k) { part[w][k] = s[k]; part[w][8 + k] = q[k]; }
    }
    __syncthreads();
    if (tid < 16) {
        float t = part[0][tid] + part[1][tid] + part[2][tid] + part[3][tid];
        atomicAdd(&st0[tid * 16], t);
    }
}

// ---- Kernel 2: x0 = bn0(feats); y1 = x0 @ W1 [P,64] f32; bn1 stats ----
__global__ __launch_bounds__(256) void k_lin1(
    const float* __restrict__ pt, const float* __restrict__ g0,
    const float* __restrict__ b0, const float* __restrict__ W1,
    const float* __restrict__ st0, float* __restrict__ y1,
    float* __restrict__ st1)
{
    __shared__ float x0s[64 * 8];
    __shared__ float w1s[8 * 64];
    __shared__ float sc0s[8], sh0s[8];
    __shared__ float red[256];
    const int tid = threadIdx.x;

    if (tid < 8) {
        float mu = st0[tid * 16] * (1.0f / CNTF);
        float var = st0[(8 + tid) * 16] * (1.0f / CNTF) - mu * mu;
        float rs = rsqrtf(var + EPS);
        sc0s[tid] = rs * g0[tid];
        sh0s[tid] = b0[tid] - mu * rs * g0[tid];
    }
    if (tid < 128) ((float4*)w1s)[tid] = ((const float4*)W1)[tid];
    const int c = tid & 63;
    const int psub = tid >> 6;
    float ssum = 0.f, ssq = 0.f;
    for (int t = 0; t < 4; ++t) {
        const int pbase = blockIdx.x * 256 + t * 64;
        __syncthreads();
        if (tid < 128) {
            float4 f = ((const float4*)(pt + (size_t)pbase * 8))[tid];
            int cc = (tid & 1) * 4;
            f.x = fmaf(f.x, sc0s[cc + 0], sh0s[cc + 0]);
            f.y = fmaf(f.y, sc0s[cc + 1], sh0s[cc + 1]);
            f.z = fmaf(f.z, sc0s[cc + 2], sh0s[cc + 2]);
            f.w = fmaf(f.w, sc0s[cc + 3], sh0s[cc + 3]);
            ((float4*)x0s)[tid] = f;
        }
        __syncthreads();
        #pragma unroll
        for (int i = 0; i < 16; ++i) {
            int pl = psub * 16 + i;
            float acc = 0.f;
            #pragma unroll
            for (int k = 0; k < 8; ++k)
                acc = fmaf(x0s[pl * 8 + k], w1s[k * 64 + c], acc);
            y1[(size_t)(pbase + pl) * 64 + c] = acc;
            ssum += acc; ssq += acc * acc;
        }
    }
    red[tid] = ssum; __syncthreads();
    if (tid < 64) atomicAdd(&st1[tid * 16],
        red[tid] + red[tid+64] + red[tid+128] + red[tid+192]);
    __syncthreads();
    red[tid] = ssq; __syncthreads();
    if (tid < 64) atomicAdd(&st1[(64 + tid) * 16],
        red[tid] + red[tid+64] + red[tid+128] + red[tid+192]);
}

// ---- Scan kernels: counts -> exclusive offsets ----
__global__ __launch_bounds__(256) void k_scan1(
    const unsigned* __restrict__ counts, unsigned* __restrict__ bsum)
{
    __shared__ unsigned sh[256];
    int t = threadIdx.x;
    sh[t] = counts[blockIdx.x * 256 + t];
    __syncthreads();
    for (int d = 128; d > 0; d >>= 1) {
        if (t < d) sh[t] += sh[t + d];
        __syncthreads();
    }
    if (t == 0) bsum[blockIdx.x] = sh[0];
}

__global__ __launch_bounds__(256) void k_scan2(
    const unsigned* __restrict__ bsum, unsigned* __restrict__ boff)
{
    __shared__ unsigned sh[256];
    int t = threadIdx.x;
    unsigned a = bsum[2*t], b = bsum[2*t+1];
    unsigned s = a + b;
    sh[t] = s; __syncthreads();
    for (int d = 1; d < 256; d <<= 1) {
        unsigned u = (t >= d) ? sh[t-d] : 0u;
        __syncthreads();
        sh[t] += u;
        __syncthreads();
    }
    unsigned excl = sh[t] - s;
    boff[2*t]   = excl;
    boff[2*t+1] = excl + a;
}

__global__ __launch_bounds__(256) void k_scan3(
    const unsigned* __restrict__ counts, const unsigned* __restrict__ boff,
    unsigned* __restrict__ offs)
{
    __shared__ unsigned sh[256];
    int t = threadIdx.x, b = blockIdx.x;
    unsigned v = counts[b*256 + t];
    sh[t] = v; __syncthreads();
    for (int d = 1; d < 256; d <<= 1) {
        unsigned u = (t >= d) ? sh[t-d] : 0u;
        __syncthreads();
        sh[t] += u;
        __syncthreads();
    }
    offs[b*256 + t] = boff[b] + sh[t] - v;
}

// ---- Fill: bucket points by voxel; also inverse perm inv[p]=slot ----
__global__ __launch_bounds__(256) void k_fill(
    const int* __restrict__ xy, const unsigned* __restrict__ offs,
    const unsigned* __restrict__ counts, unsigned* __restrict__ cur,
    unsigned* __restrict__ pidf, unsigned* __restrict__ send,
    unsigned* __restrict__ skey, unsigned* __restrict__ inv)
{
    int p = blockIdx.x * 256 + threadIdx.x;
    int key = (p >> 16) * HWSZ + xy[2*p] * WGRID + xy[2*p + 1];
    unsigned o = offs[key];
    unsigned r = atomicAdd(&cur[key], 1u);
    unsigned slot = o + r;
    pidf[slot] = (unsigned)p | (r == 0 ? 0x80000000u : 0u);
    send[slot] = o + counts[key];
    skey[slot] = (unsigned)key;
    inv[p] = slot;
}

// ---- Kernel 3 (MFMA): y2 = bf16(relu(bn1(y1)) @ W2) [P,128]; bn2 stats ----
__global__ __launch_bounds__(256, 2) void k_lin2(
    const float* __restrict__ y1, const float* __restrict__ g1,
    const float* __restrict__ b1, const uint4* __restrict__ W2F,
    const float* __restrict__ st1, unsigned short* __restrict__ y2,
    float* __restrict__ st2)
{
    __shared__ uint4 w2s[1024];        // 16 KB
    __shared__ float sc1s[64], sh1s[64];
    const int tid = threadIdx.x, l = tid & 63, w = tid >> 6;
    if (tid < 64) {
        float mu = st1[tid * 16] * (1.0f / CNTF);
        float var = st1[(64 + tid) * 16] * (1.0f / CNTF) - mu * mu;
        float rs = rsqrtf(var + EPS);
        sc1s[tid] = rs * g1[tid];
        sh1s[tid] = b1[tid] - mu * rs * g1[tid];
    }
    #pragma unroll
    for (int r = 0; r < 4; ++r) w2s[r * 256 + tid] = W2F[r * 256 + tid];
    __syncthreads();
    const int n = l & 31, q = l >> 5;
    float s_acc[16], q_acc[16];
    #pragma unroll
    for (int r = 0; r < 16; ++r) { s_acc[r] = 0.f; q_acc[r] = 0.f; }

    for (int t = 0; t < 8; ++t) {
        const int p = (blockIdx.x * 8 + t) * 32 + n;
        const float* yrow = y1 + (size_t)p * 64 + q * 8;
        bf16x8 Bf[4];
        #pragma unroll
        for (int ks = 0; ks < 4; ++ks) {
            float4 v0 = *(const float4*)(yrow + ks * 16);
            float4 v1 = *(const float4*)(yrow + ks * 16 + 4);
            int k0 = ks * 16 + q * 8;
            float e[8] = {v0.x,v0.y,v0.z,v0.w,v1.x,v1.y,v1.z,v1.w};
            union { bf16x8 v; unsigned u[4]; } cv;
            #pragma unroll
            for (int jj = 0; jj < 4; ++jj) {
                float a0 = fmaxf(fmaf(e[2*jj],   sc1s[k0+2*jj],   sh1s[k0+2*jj]),   0.f);
                float a1 = fmaxf(fmaf(e[2*jj+1], sc1s[k0+2*jj+1], sh1s[k0+2*jj+1]), 0.f);
                cv.u[jj] = f2bf(a0) | (f2bf(a1) << 16);
            }
            Bf[ks] = cv.v;
        }
        f32x16 acc;
        #pragma unroll
        for (int r = 0; r < 16; ++r) acc[r] = 0.f;
        #pragma unroll
        for (int ks = 0; ks < 4; ++ks) {
            union { uint4 u; bf16x8 v; } av;
            av.u = w2s[(w * 4 + ks) * 64 + l];
            acc = __builtin_amdgcn_mfma_f32_32x32x16_bf16(av.v, Bf[ks], acc, 0, 0, 0);
        }
        #pragma unroll
        for (int g = 0; g < 4; ++g) {
            int ch0 = w * 32 + 8 * g + 4 * q;
            ushort4 pk;
            pk.x = (unsigned short)f2bf(acc[4*g+0]);
            pk.y = (unsigned short)f2bf(acc[4*g+1]);
            pk.z = (unsigned short)f2bf(acc[4*g+2]);
            pk.w = (unsigned short)f2bf(acc[4*g+3]);
            *(ushort4*)(y2 + (size_t)p * 128 + ch0) = pk;
        }
        #pragma unroll
        for (int r = 0; r < 16; ++r) { s_acc[r] += acc[r]; q_acc[r] += acc[r]*acc[r]; }
    }
    #pragma unroll
    for (int r = 0; r < 16; ++r) {
        float s = s_acc[r], sq = q_acc[r];
        #pragma unroll
        for (int off = 16; off > 0; off >>= 1) {
            s  += __shfl_xor(s, off);
            sq += __shfl_xor(sq, off);
        }
        if ((l & 31) == 0) {
            int ch = w * 32 + (r & 3) + 8 * (r >> 2) + 4 * q;
            atomicAdd(&st2[ch * 16], s);
            atomicAdd(&st2[(128 + ch) * 16], sq);
        }
    }
}

// ---- Kernel 4 (MFMA): y3F = frag-layout(bf16(y2f @ W3)) at slot order ----
__global__ __launch_bounds__(256, 2) void k_lin3(
    const unsigned short* __restrict__ y2f, const uint4* __restrict__ W3F,
    const unsigned* __restrict__ inv, uint4* __restrict__ y3F,
    float* __restrict__ st3)
{
    __shared__ uint4 w3s[4096];        // 64 KB
    const int tid = threadIdx.x, l = tid & 63, w = tid >> 6;
    #pragma unroll
    for (int r = 0; r < 16; ++r) w3s[r * 256 + tid] = W3F[r * 256 + tid];
    __syncthreads();
    const int n = l & 31, q = l >> 5;
    float s_acc[32], q_acc[32];
    #pragma unroll
    for (int r = 0; r < 32; ++r) { s_acc[r] = 0.f; q_acc[r] = 0.f; }

    for (int t = 0; t < 8; ++t) {
        const int p = (blockIdx.x * 8 + t) * 32 + n;
        const unsigned short* yrow = y2f + (size_t)p * 128 + q * 8;
        bf16x8 Bf[8];
        #pragma unroll
        for (int ks = 0; ks < 8; ++ks) {
            union { uint4 u; bf16x8 v; } bv;
            bv.u = *(const uint4*)(yrow + ks * 16);
            Bf[ks] = bv.v;
        }
        f32x16 acc[2];
        #pragma unroll
        for (int i = 0; i < 2; ++i)
            #pragma unroll
            for (int r = 0; r < 16; ++r) acc[i][r] = 0.f;
        #pragma unroll
        for (int ks = 0; ks < 8; ++ks) {
            #pragma unroll
            for (int i = 0; i < 2; ++i) {
                union { uint4 u; bf16x8 v; } av;
                av.u = w3s[((w * 2 + i) * 8 + ks) * 64 + l];
                acc[i] = __builtin_amdgcn_mfma_f32_32x32x16_bf16(av.v, Bf[ks], acc[i], 0, 0, 0);
            }
        }
        #pragma unroll
        for (int i = 0; i < 2; ++i)
            #pragma unroll
            for (int r = 0; r < 16; ++r) {
                s_acc[i*16+r] += acc[i][r];
                q_acc[i*16+r] += acc[i][r] * acc[i][r];
            }
        const unsigned slotn = inv[p];
        const int fb = (int)(slotn >> 5) * 16;       // frag base of tile
        const int li = (int)(slotn & 31) + 32 * q;   // lane in target frag
        #pragma unroll
        for (int i = 0; i < 2; ++i) {
            #pragma unroll
            for (int s = 0; s < 2; ++s) {
                float V[8];
                #pragma unroll
                for (int j = 0; j < 4; ++j) {
                    float tmp = q ? acc[i][8*s + j] : acc[i][8*s + 4 + j];
                    float got = __shfl_xor(tmp, 32);
                    V[j]     = q ? got : acc[i][8*s + j];
                    V[4 + j] = q ? acc[i][8*s + 4 + j] : got;
                }
                uint4 pk;
                pk.x = f2bf(V[0]) | (f2bf(V[1]) << 16);
                pk.y = f2bf(V[2]) | (f2bf(V[3]) << 16);
                pk.z = f2bf(V[4]) | (f2bf(V[5]) << 16);
                pk.w = f2bf(V[6]) | (f2bf(V[7]) << 16);
                y3F[(size_t)(fb + w * 4 + 2 * i + s) * 64 + li] = pk;
            }
        }
    }
    #pragma unroll
    for (int i = 0; i < 2; ++i)
        #pragma unroll
        for (int r = 0; r < 16; ++r) {
            float s = s_acc[i*16+r], sq = q_acc[i*16+r];
            #pragma unroll
            for (int off = 16; off > 0; off >>= 1) {
                s  += __shfl_xor(s, off);
                sq += __shfl_xor(sq, off);
            }
            if ((l & 31) == 0) {
                int ch = (w * 2 + i) * 32 + (r & 3) + 8 * (r >> 2) + 4 * q;
                atomicAdd(&st3[ch * 16], s);
                atomicAdd(&st3[(256 + ch) * 16], sq);
            }
        }
}

// ---- Kernel 5 (MFMA): LDS-staged fold+X GEMM + register segmented max ----
// 1024 blocks (groups of 4 + 1 overlap). Tile staged to LDS once per window
// with bn3 fold applied during staging (coeffs in LDS from padded st3; same
// math/rounding as the old k_foldf). Waves read frag rows from LDS. sub loop
// unroll 1; carry in explicit LDS; store loop fully unrolled.
__global__ __launch_bounds__(256, 2) void k_smax(
    const uint4* __restrict__ y3F, const uint4* __restrict__ W4F,
    const float* __restrict__ g3, const float* __restrict__ b3,
    const float* __restrict__ st3, const unsigned* __restrict__ pidf,
    const unsigned* __restrict__ send, const unsigned* __restrict__ skey,
    unsigned short* __restrict__ pooled)
{
    __shared__ float s0c_s[4 * 256];   // 4 KB carry; [sub*256+tid], no sync
    __shared__ float sc3s[256], sh3s[256];
    __shared__ uint4 xs[1024];         // 16 KB folded tile
    const int tid = threadIdx.x, l = tid & 63, w = tid >> 6;
    const int wg = blockIdx.x;         // 0..1023
    const int q = l >> 5;

    {
        float mu = st3[tid * 16] * (1.0f / CNTF);
        float var = st3[(256 + tid) * 16] * (1.0f / CNTF) - mu * mu;
        float rs = rsqrtf(var + EPS);
        float s = rs * g3[tid];
        sc3s[tid] = s;
        sh3s[tid] = b3[tid] - mu * s;
    }
    #pragma unroll
    for (int sub = 0; sub < 4; ++sub) s0c_s[sub * 256 + tid] = -3.4e38f;
    __syncthreads();

    #pragma unroll 1
    for (int t = 4; t >= 0; --t) {     // t=4 is carry-only overlap window
        const int p0 = (wg * 4 + t) * 32;
        const int pos = p0 + (l & 31);
        const int sp = pos < P_TOT ? pos : P_TOT - 1;
        const unsigned pf = pidf[sp];
        const unsigned e_l = send[sp];
        const unsigned key_l = skey[sp];
        const unsigned cmask =
            (unsigned)__ballot((unsigned)(pos + 1) < e_l);
        const unsigned fmask =
            (unsigned)__ballot((pf & 0x80000000u) != 0u);
        // stage tile -> LDS with bn3 fold (all 4 waves share the tile)
        const int tt = (wg * 4 + t) < 4096 ? (wg * 4 + t) : 4095;
        __syncthreads();               // prior window's readers done
        #pragma unroll
        for (int r = 0; r < 4; ++r) {
            int idx = r * 256 + tid;
            uint4 e = y3F[(size_t)tt * 1024 + idx];
            int ch0 = ((idx >> 6) & 15) * 16 + ((idx >> 5) & 1) * 8;
            unsigned eu[4] = {e.x, e.y, e.z, e.w};
            unsigned ou[4];
            #pragma unroll
            for (int jj = 0; jj < 4; ++jj) {
                float a0 = fmaxf(fmaf(bf2f(eu[jj] & 0xFFFFu),
                                      sc3s[ch0+2*jj],   sh3s[ch0+2*jj]),   0.f);
                float a1 = fmaxf(fmaf(bf2f(eu[jj] >> 16),
                                      sc3s[ch0+2*jj+1], sh3s[ch0+2*jj+1]), 0.f);
                ou[jj] = f2bf(a0) | (f2bf(a1) << 16);
            }
            xs[idx] = make_uint4(ou[0], ou[1], ou[2], ou[3]);
        }
        __syncthreads();

        #pragma unroll 1
        for (int sub = 0; sub < 4; ++sub) {
            const int nt = sub * 4 + w;          // channel tile (32 ch)
            f32x16 acc;
            #pragma unroll
            for (int r = 0; r < 16; ++r) acc[r] = 0.f;
            #pragma unroll
            for (int ks = 0; ks < 16; ++ks) {
                union { uint4 u; bf16x8 v; } xv, wv;
                xv.u = xs[ks * 64 + l];
                wv.u = W4F[(size_t)(nt * 16 + ks) * 64 + l];
                // A=X (M=points), B=W4 (N=channels) -> C: lane=ch, reg=point
                acc = __builtin_amdgcn_mfma_f32_32x32x16_bf16(xv.v, wv.v, acc, 0, 0, 0);
            }
            // half-exchange: v[point 0..31] per lane (lane = channel)
            float v[32];
            #pragma unroll
            for (int r = 0; r < 16; ++r) {
                int base = (r & 3) + 8 * (r >> 2);
                float o = __shfl_xor(acc[r], 32);
                v[base]     = q ? o : acc[r];
                v[base + 4] = q ? acc[r] : o;
            }
            // segmented suffix-max, SGPR-bit conditions, compile-time indices
            if ((cmask >> 31) & 1)
                v[31] = fmaxf(v[31], s0c_s[sub * 256 + tid]);
            #pragma unroll
            for (int m = 30; m >= 0; --m)
                if ((cmask >> m) & 1) v[m] = fmaxf(v[m], v[m + 1]);
            s0c_s[sub * 256 + tid] = v[0];
            // stores: fully unrolled, wave-uniform bit guard, v[m] compile-time
            if (t < 4) {
                #pragma unroll
                for (int m = 0; m < 32; ++m) {
                    if ((fmask >> m) & 1) {
                        unsigned km = (unsigned)
                            __builtin_amdgcn_readlane((int)key_l, m);
                        if ((m >> 4) == q)
                            pooled[(size_t)km * 512 + nt * 32 + (l & 31)] =
                                (unsigned short)f2bf(v[m]);
                    }
                }
            }
        }
    }
}

// ---- Kernel 6 (MFMA): comp = relu(pooled @ Wc); transpose to [B,CMP,H,W] ----
__global__ __launch_bounds__(256, 4) void k_out(
    const unsigned short* __restrict__ pooled, const unsigned* __restrict__ counts,
    const uint4* __restrict__ WcF, float* __restrict__ out)
{
    __shared__ uint4 wcs[2048];        // 32 KB: full WcF
    const int tid = threadIdx.x, l = tid & 63, w = tid >> 6;
    const int sbase = blockIdx.x * 128;
    #pragma unroll
    for (int r = 0; r < 8; ++r) wcs[r * 256 + tid] = WcF[r * 256 + tid];
    __syncthreads();
    const int n = l & 31, q = l >> 5;
    const int s = sbase + w * 32 + n;
    const bool occ = counts[s] > 0;
    // unoccupied voxels read the (hot) line-0 row instead of cold poison
    const unsigned short* prow =
        pooled + (occ ? (size_t)s * 512 : (size_t)0) + q * 8;
    f32x16 acc;
    #pragma unroll
    for (int r = 0; r < 16; ++r) acc[r] = 0.f;

    for (int ks = 0; ks < 32; ++ks) {
        union { uint4 u; bf16x8 v; } bv;
        bv.u = *(const uint4*)(prow + ks * 16);   // raw bf16 IS the B frag
        union { uint4 u; bf16x8 v; } av;
        av.u = wcs[ks * 64 + l];
        acc = __builtin_amdgcn_mfma_f32_32x32x16_bf16(av.v, bv.v, acc, 0, 0, 0);
    }
    const int b = s >> 16, hw = s & 65535;
    #pragma unroll
    for (int r = 0; r < 16; ++r) {
        int ch = (r & 3) + 8 * (r >> 2) + 4 * q;
        float x = occ ? fmaxf(acc[r], 0.f) : 0.f;
        out[(size_t)b * (32 * HWSZ) + (size_t)ch * HWSZ + hw] = x;
    }
}

extern "C" void kernel_launch(void* const* d_in, const int* in_sizes, int n_in,
                              void* d_out, int out_size, void* d_ws, size_t ws_size,
                              hipStream_t stream) {
    const float* pt = (const float*)d_in[0];
    const float* g0 = (const float*)d_in[1];
    const float* b0 = (const float*)d_in[2];
    const float* W1 = (const float*)d_in[3];
    const float* g1 = (const float*)d_in[4];
    const float* b1 = (const float*)d_in[5];
    const float* W2 = (const float*)d_in[6];
    const float* g2 = (const float*)d_in[7];
    const float* b2 = (const float*)d_in[8];
    const float* W3 = (const float*)d_in[9];
    const float* g3 = (const float*)d_in[10];
    const float* b3 = (const float*)d_in[11];
    const float* W4 = (const float*)d_in[12];
    const float* Wc = (const float*)d_in[13];
    const int*   xy = (const int*)d_in[14];
    float* out = (float*)d_out;

    char* ws = (char*)d_ws;
    uint4*          y3F    = (uint4*)(ws + OFF_Y3);
    float*          y1     = (float*)(ws + OFF_Y1);
    unsigned short* y2     = (unsigned short*)(ws + OFF_Y2);
    unsigned short* pool16 = (unsigned short*)(ws + OFF_POOL);
    unsigned*       counts = (unsigned*)(ws + OFF_CNT);
    float*          st     = (float*)(ws + OFF_ST);
    unsigned*       offs   = (unsigned*)(ws + OFF_OFFS);
    unsigned*       cur    = (unsigned*)(ws + OFF_CUR);
    unsigned*       bsum   = (unsigned*)(ws + OFF_BSUM);
    unsigned*       pidf   = (unsigned*)(ws + OFF_PIDF);
    unsigned*       send   = (unsigned*)(ws + OFF_SEND);
    unsigned*       skey   = (unsigned*)(ws + OFF_SKEY);
    unsigned*       inv    = (unsigned*)(ws + OFF_INV);
    uint4* W3F = (uint4*)(ws + OFF_W3F);
    uint4* W4F = (uint4*)(ws + OFF_W4F);
    uint4* WcF = (uint4*)(ws + OFF_WCF);
    uint4* W2F = (uint4*)(ws + OFF_W2F);
    float* scsh = (float*)(ws + OFF_SCSH);
    float* sc2 = scsh;       float* sh2 = scsh + 128;
    // padded stats: one 64B line per entry (entry i at st[i*16])
    float* st0 = st;            // 16 entries
    float* st1 = st + 256;      // 128 entries
    float* st2 = st + 2304;     // 256 entries
    float* st3 = st + 6400;     // 512 entries

    // zero counts+stats+offs+cur in one contiguous pass (1638400 B)
    k_zero<<<400, 256, 0, stream>>>((uint4*)(ws + OFF_CNT), 102400);
    // weights -> bf16 frag layout
    k_prepw<<<92, 256, 0, stream>>>(W2, W3, W4, Wc, W2F, W3F, W4F, WcF);

    k_stats0<<<512, 256, 0, stream>>>(pt, xy, st0, counts);
    // counting sort: counts -> offs -> slot fill (+ inverse perm)
    k_scan1<<<512, 256, 0, stream>>>(counts, bsum);
    k_scan2<<<1,   256, 0, stream>>>(bsum, bsum + 512);
    k_scan3<<<512, 256, 0, stream>>>(counts, bsum + 512, offs);
    k_fill<<<512, 256, 0, stream>>>(xy, offs, counts, cur, pidf, send, skey, inv);

    k_lin1<<<512, 256, 0, stream>>>(pt, g0, b0, W1, st0, y1, st1);
    k_lin2<<<512, 256, 0, stream>>>(y1, g1, b1, W2F, st1, y2, st2);
    k_bnprep<<<1, 256, 0, stream>>>(st2, g2, b2, sc2, sh2, 128);
    k_fold<<<8192, 256, 0, stream>>>(y2, sc2, sh2, 128, 2097152);
    k_lin3<<<512, 256, 0, stream>>>(y2, W3F, inv, y3F, st3);

    k_smax<<<1024, 256, 0, stream>>>(y3F, W4F, g3, b3, st3,
                                     pidf, send, skey, pool16);
    k_out<<<S_TOT / 128, 256, 0, stream>>>(pool16, counts, WcF, out);
}

// Round 18
// 401.635 us; speedup vs baseline: 1.0492x; 1.0492x over previous
//
#include <hip/hip_runtime.h>
#include <cstdint>
#include <cstddef>

// PPmodel_all_preprocess — MI355X, round 18: revert k_smax to round-16 body
// (registers, no LDS tile staging); y1 f32 -> bf16 as the one tail change.
//
// Round-17: LDS-staging the (already coalesced, L1-hot) tile + 2 barriers per
// window serialized the 4 waves -> occupancy 37->23%, k_smax 110->151.
// Lesson: LDS staging pays only when it REMOVES scattered traffic, not when
// loads are already friendly. Round-18: round-16 k_smax verbatim (best
// measured 110us), k_bnprep+k_foldf restored, and y1 stored bf16 (k_lin1
// stats still from fp32 accs; k_lin2 B-frag build from bf16 source per the
// proven round-13 pattern) -> halves 66MB of y1 traffic.
//
// Workspace: y3F | y1(bf16) | y2 | pooled(alias) | counts | stats(x16) |
//   offs | cur | bsum | pidf | send | skey | inv | W3F | W4F | WcF | W2F | scsh

#define P_TOT  131072
#define HWSZ   65536
#define WGRID  256
#define S_TOT  131072
#define EPS    1e-5f
#define CNTF   131072.0f

#define OFF_Y3    0ull
#define OFF_Y1    67108864ull
#define OFF_Y2    100663296ull
#define OFF_POOL  67108864ull
#define OFF_CNT   201326592ull
#define OFF_ST    201850880ull
#define OFF_OFFS  201916416ull
#define OFF_CUR   202440704ull
#define OFF_BSUM  202964992ull
#define OFF_PIDF  202969088ull
#define OFF_SEND  203493376ull
#define OFF_SKEY  204017664ull
#define OFF_INV   204541952ull
#define OFF_W3F   205066240ull
#define OFF_W4F   205131776ull
#define OFF_WCF   205393920ull
#define OFF_W2F   205426688ull
#define OFF_SCSH  205443072ull

typedef __attribute__((ext_vector_type(8)))  short bf16x8;
typedef __attribute__((ext_vector_type(16))) float f32x16;

// ---- bf16 helpers (manual, RNE) ----
__device__ __forceinline__ unsigned f2bf(float f) {
    unsigned u = __float_as_uint(f);
    return (u + 0x7FFFu + ((u >> 16) & 1u)) >> 16;   // RNE, finite inputs
}
__device__ __forceinline__ float bf2f(unsigned h) {
    return __uint_as_float(h << 16);
}

// ---- zero-fill (graph-capture-safe memset replacement) ----
__global__ __launch_bounds__(256) void k_zero(uint4* __restrict__ p, int n_u4) {
    int i = blockIdx.x * blockDim.x + threadIdx.x;
    if (i < n_u4) p[i] = make_uint4(0u, 0u, 0u, 0u);
}

// ---- Prep: W2/W3/W4/Wc -> bf16 frag layout (32x32x16 operand) ----
__global__ __launch_bounds__(256) void k_prepw(
    const float* __restrict__ W2, const float* __restrict__ W3,
    const float* __restrict__ W4, const float* __restrict__ Wc,
    uint4* __restrict__ W2F, uint4* __restrict__ W3F,
    uint4* __restrict__ W4F, uint4* __restrict__ WcF)
{
    int gw = (blockIdx.x * 256 + threadIdx.x) >> 6;
    int l = threadIdx.x & 63;
    const float* W; uint4* dst; int M, mt, ks, fi;
    if (gw < 64)       { fi = gw;       W = W3; dst = W3F; M = 256; mt = fi >> 3; ks = fi & 7;  }
    else if (gw < 320) { fi = gw - 64;  W = W4; dst = W4F; M = 512; mt = fi >> 4; ks = fi & 15; }
    else if (gw < 352) { fi = gw - 320; W = Wc; dst = WcF; M = 32;  mt = 0;      ks = fi;      }
    else               { fi = gw - 352; W = W2; dst = W2F; M = 128; mt = fi >> 2; ks = fi & 3;  }
    int m = mt * 32 + (l & 31);
    int k0 = ks * 16 + (l >> 5) * 8;
    unsigned p[4];
    #pragma unroll
    for (int jj = 0; jj < 4; ++jj) {
        unsigned lo = f2bf(W[(size_t)(k0 + 2*jj)     * M + m]);
        unsigned hi = f2bf(W[(size_t)(k0 + 2*jj + 1) * M + m]);
        p[jj] = lo | (hi << 16);
    }
    dst[(size_t)fi * 64 + l] = make_uint4(p[0], p[1], p[2], p[3]);
}

// ---- bn fold coefficients: sc[c] = rs*g, sh[c] = b - mu*sc ----
__global__ __launch_bounds__(256) void k_bnprep(
    const float* __restrict__ st, const float* __restrict__ g,
    const float* __restrict__ b, float* __restrict__ sc,
    float* __restrict__ sh, int nch)
{
    int c = blockIdx.x * 256 + threadIdx.x;
    if (c >= nch) return;
    float mu = st[c * 16] * (1.0f / CNTF);
    float var = st[(nch + c) * 16] * (1.0f / CNTF) - mu * mu;
    float rs = rsqrtf(var + EPS);
    float s = rs * g[c];
    sc[c] = s;
    sh[c] = b[c] - mu * s;
}

// ---- In-place fold (row layout): y = bf16(relu(y*sc+sh)), nch pow2 ----
__global__ __launch_bounds__(256) void k_fold(
    unsigned short* __restrict__ y, const float* __restrict__ sc,
    const float* __restrict__ sh, int nch, int n_u4)
{
    int i = blockIdx.x * 256 + threadIdx.x;
    if (i >= n_u4) return;
    int ch0 = (i * 8) & (nch - 1);
    float4 s0 = *(const float4*)(sc + ch0), s1 = *(const float4*)(sc + ch0 + 4);
    float4 h0 = *(const float4*)(sh + ch0), h1 = *(const float4*)(sh + ch0 + 4);
    float scv[8] = {s0.x,s0.y,s0.z,s0.w,s1.x,s1.y,s1.z,s1.w};
    float shv[8] = {h0.x,h0.y,h0.z,h0.w,h1.x,h1.y,h1.z,h1.w};
    uint4 e = ((const uint4*)y)[i];
    unsigned eu[4] = {e.x, e.y, e.z, e.w};
    unsigned ou[4];
    #pragma unroll
    for (int jj = 0; jj < 4; ++jj) {
        float x0 = fmaxf(fmaf(bf2f(eu[jj] & 0xFFFFu), scv[2*jj],   shv[2*jj]),   0.f);
        float x1 = fmaxf(fmaf(bf2f(eu[jj] >> 16),     scv[2*jj+1], shv[2*jj+1]), 0.f);
        ou[jj] = f2bf(x0) | (f2bf(x1) << 16);
    }
    ((uint4*)y)[i] = make_uint4(ou[0], ou[1], ou[2], ou[3]);
}

// ---- In-place fold (FRAG layout, 256 ch): ch from (frag,lane) ----
__global__ __launch_bounds__(256) void k_foldf(
    unsigned short* __restrict__ y, const float* __restrict__ sc,
    const float* __restrict__ sh, int n_u4)
{
    int i = blockIdx.x * 256 + threadIdx.x;
    if (i >= n_u4) return;
    int ch0 = ((i >> 6) & 15) * 16 + ((i >> 5) & 1) * 8;
    float4 s0 = *(const float4*)(sc + ch0), s1 = *(const float4*)(sc + ch0 + 4);
    float4 h0 = *(const float4*)(sh + ch0), h1 = *(const float4*)(sh + ch0 + 4);
    float scv[8] = {s0.x,s0.y,s0.z,s0.w,s1.x,s1.y,s1.z,s1.w};
    float shv[8] = {h0.x,h0.y,h0.z,h0.w,h1.x,h1.y,h1.z,h1.w};
    uint4 e = ((const uint4*)y)[i];
    unsigned eu[4] = {e.x, e.y, e.z, e.w};
    unsigned ou[4];
    #pragma unroll
    for (int jj = 0; jj < 4; ++jj) {
        float x0 = fmaxf(fmaf(bf2f(eu[jj] & 0xFFFFu), scv[2*jj],   shv[2*jj]),   0.f);
        float x1 = fmaxf(fmaf(bf2f(eu[jj] >> 16),     scv[2*jj+1], shv[2*jj+1]), 0.f);
        ou[jj] = f2bf(x0) | (f2bf(x1) << 16);
    }
    ((uint4*)y)[i] = make_uint4(ou[0], ou[1], ou[2], ou[3]);
}

// ---- Kernel 1: bn0 raw stats (block-reduced) + per-voxel point counts ----
__global__ __launch_bounds__(256) void k_stats0(
    const float* __restrict__ pt, const int* __restrict__ xy,
    float* __restrict__ st0, unsigned* __restrict__ counts)
{
    __shared__ float part[4][16];
    const int tid = threadIdx.x;
    const int p = blockIdx.x * 256 + tid;
    const float4* f4 = (const float4*)(pt + (size_t)p * 8);
    float4 a = f4[0], b = f4[1];
    float v[8] = {a.x,a.y,a.z,a.w,b.x,b.y,b.z,b.w};
    int key = (p >> 16) * HWSZ + xy[2*p] * WGRID + xy[2*p + 1];
    atomicAdd(&counts[key], 1u);
    float s[8], q[8];
    #pragma unroll
    for (int k = 0; k < 8; ++k) { s[k] = v[k]; q[k] = v[k]*v[k]; }
    #pragma unroll
    for (int k = 0; k < 8; ++k) {
        #pragma unroll
        for (int off = 32; off > 0; off >>= 1) {
            s[k] += __shfl_down(s[k], off);
            q[k] += __shfl_down(q[k], off);
        }
    }
    if ((tid & 63) == 0) {
        int w = tid >> 6;
        #pragma unroll
        for (int k = 0; k < 8; ++k) { part[w][k] = s[k]; part[w][8 + k] = q[k]; }
    }
    __syncthreads();
    if (tid < 16) {
        float t = part[0][tid] + part[1][tid] + part[2][tid] + part[3][tid];
        atomicAdd(&st0[tid * 16], t);
    }
}

// ---- Kernel 2: x0 = bn0(feats); y1 = bf16(x0 @ W1) [P,64]; bn1 stats ----
__global__ __launch_bounds__(256) void k_lin1(
    const float* __restrict__ pt, const float* __restrict__ g0,
    const float* __restrict__ b0, const float* __restrict__ W1,
    const float* __restrict__ st0, unsigned short* __restrict__ y1,
    float* __restrict__ st1)
{
    __shared__ float x0s[64 * 8];
    __shared__ float w1s[8 * 64];
    __shared__ float sc0s[8], sh0s[8];
    __shared__ float red[256];
    const int tid = threadIdx.x;

    if (tid < 8) {
        float mu = st0[tid * 16] * (1.0f / CNTF);
        float var = st0[(8 + tid) * 16] * (1.0f / CNTF) - mu * mu;
        float rs = rsqrtf(var + EPS);
        sc0s[tid] = rs * g0[tid];
        sh0s[tid] = b0[tid] - mu * rs * g0[tid];
    }
    if (tid < 128) ((float4*)w1s)[tid] = ((const float4*)W1)[tid];
    const int c = tid & 63;
    const int psub = tid >> 6;
    float ssum = 0.f, ssq = 0.f;
    for (int t = 0; t < 4; ++t) {
        const int pbase = blockIdx.x * 256 + t * 64;
        __syncthreads();
        if (tid < 128) {
            float4 f = ((const float4*)(pt + (size_t)pbase * 8))[tid];
            int cc = (tid & 1) * 4;
            f.x = fmaf(f.x, sc0s[cc + 0], sh0s[cc + 0]);
            f.y = fmaf(f.y, sc0s[cc + 1], sh0s[cc + 1]);
            f.z = fmaf(f.z, sc0s[cc + 2], sh0s[cc + 2]);
            f.w = fmaf(f.w, sc0s[cc + 3], sh0s[cc + 3]);
            ((float4*)x0s)[tid] = f;
        }
        __syncthreads();
        #pragma unroll
        for (int i = 0; i < 16; ++i) {
            int pl = psub * 16 + i;
            float acc = 0.f;
            #pragma unroll
            for (int k = 0; k < 8; ++k)
                acc = fmaf(x0s[pl * 8 + k], w1s[k * 64 + c], acc);
            y1[(size_t)(pbase + pl) * 64 + c] = (unsigned short)f2bf(acc);
            ssum += acc; ssq += acc * acc;
        }
    }
    red[tid] = ssum; __syncthreads();
    if (tid < 64) atomicAdd(&st1[tid * 16],
        red[tid] + red[tid+64] + red[tid+128] + red[tid+192]);
    __syncthreads();
    red[tid] = ssq; __syncthreads();
    if (tid < 64) atomicAdd(&st1[(64 + tid) * 16],
        red[tid] + red[tid+64] + red[tid+128] + red[tid+192]);
}

// ---- Scan kernels: counts -> exclusive offsets ----
__global__ __launch_bounds__(256) void k_scan1(
    const unsigned* __restrict__ counts, unsigned* __restrict__ bsum)
{
    __shared__ unsigned sh[256];
    int t = threadIdx.x;
    sh[t] = counts[blockIdx.x * 256 + t];
    __syncthreads();
    for (int d = 128; d > 0; d >>= 1) {
        if (t < d) sh[t] += sh[t + d];
        __syncthreads();
    }
    if (t == 0) bsum[blockIdx.x] = sh[0];
}

__global__ __launch_bounds__(256) void k_scan2(
    const unsigned* __restrict__ bsum, unsigned* __restrict__ boff)
{
    __shared__ unsigned sh[256];
    int t = threadIdx.x;
    unsigned a = bsum[2*t], b = bsum[2*t+1];
    unsigned s = a + b;
    sh[t] = s; __syncthreads();
    for (int d = 1; d < 256; d <<= 1) {
        unsigned u = (t >= d) ? sh[t-d] : 0u;
        __syncthreads();
        sh[t] += u;
        __syncthreads();
    }
    unsigned excl = sh[t] - s;
    boff[2*t]   = excl;
    boff[2*t+1] = excl + a;
}

__global__ __launch_bounds__(256) void k_scan3(
    const unsigned* __restrict__ counts, const unsigned* __restrict__ boff,
    unsigned* __restrict__ offs)
{
    __shared__ unsigned sh[256];
    int t = threadIdx.x, b = blockIdx.x;
    unsigned v = counts[b*256 + t];
    sh[t] = v; __syncthreads();
    for (int d = 1; d < 256; d <<= 1) {
        unsigned u = (t >= d) ? sh[t-d] : 0u;
        __syncthreads();
        sh[t] += u;
        __syncthreads();
    }
    offs[b*256 + t] = boff[b] + sh[t] - v;
}

// ---- Fill: bucket points by voxel; also inverse perm inv[p]=slot ----
__global__ __launch_bounds__(256) void k_fill(
    const int* __restrict__ xy, const unsigned* __restrict__ offs,
    const unsigned* __restrict__ counts, unsigned* __restrict__ cur,
    unsigned* __restrict__ pidf, unsigned* __restrict__ send,
    unsigned* __restrict__ skey, unsigned* __restrict__ inv)
{
    int p = blockIdx.x * 256 + threadIdx.x;
    int key = (p >> 16) * HWSZ + xy[2*p] * WGRID + xy[2*p + 1];
    unsigned o = offs[key];
    unsigned r = atomicAdd(&cur[key], 1u);
    unsigned slot = o + r;
    pidf[slot] = (unsigned)p | (r == 0 ? 0x80000000u : 0u);
    send[slot] = o + counts[key];
    skey[slot] = (unsigned)key;
    inv[p] = slot;
}

// ---- Kernel 3 (MFMA): y2 = bf16(relu(bn1(y1bf)) @ W2) [P,128]; bn2 stats ----
__global__ __launch_bounds__(256, 2) void k_lin2(
    const unsigned short* __restrict__ y1, const float* __restrict__ g1,
    const float* __restrict__ b1, const uint4* __restrict__ W2F,
    const float* __restrict__ st1, unsigned short* __restrict__ y2,
    float* __restrict__ st2)
{
    __shared__ uint4 w2s[1024];        // 16 KB
    __shared__ float sc1s[64], sh1s[64];
    const int tid = threadIdx.x, l = tid & 63, w = tid >> 6;
    if (tid < 64) {
        float mu = st1[tid * 16] * (1.0f / CNTF);
        float var = st1[(64 + tid) * 16] * (1.0f / CNTF) - mu * mu;
        float rs = rsqrtf(var + EPS);
        sc1s[tid] = rs * g1[tid];
        sh1s[tid] = b1[tid] - mu * rs * g1[tid];
    }
    #pragma unroll
    for (int r = 0; r < 4; ++r) w2s[r * 256 + tid] = W2F[r * 256 + tid];
    __syncthreads();
    const int n = l & 31, q = l >> 5;
    float s_acc[16], q_acc[16];
    #pragma unroll
    for (int r = 0; r < 16; ++r) { s_acc[r] = 0.f; q_acc[r] = 0.f; }

    for (int t = 0; t < 8; ++t) {
        const int p = (blockIdx.x * 8 + t) * 32 + n;
        const unsigned short* yrow = y1 + (size_t)p * 64 + q * 8;
        bf16x8 Bf[4];
        #pragma unroll
        for (int ks = 0; ks < 4; ++ks) {
            uint4 e = *(const uint4*)(yrow + ks * 16);
            int k0 = ks * 16 + q * 8;
            unsigned eu[4] = {e.x, e.y, e.z, e.w};
            union { bf16x8 v; unsigned u[4]; } cv;
            #pragma unroll
            for (int jj = 0; jj < 4; ++jj) {
                float a0 = fmaxf(fmaf(bf2f(eu[jj] & 0xFFFFu),
                                      sc1s[k0+2*jj],   sh1s[k0+2*jj]),   0.f);
                float a1 = fmaxf(fmaf(bf2f(eu[jj] >> 16),
                                      sc1s[k0+2*jj+1], sh1s[k0+2*jj+1]), 0.f);
                cv.u[jj] = f2bf(a0) | (f2bf(a1) << 16);
            }
            Bf[ks] = cv.v;
        }
        f32x16 acc;
        #pragma unroll
        for (int r = 0; r < 16; ++r) acc[r] = 0.f;
        #pragma unroll
        for (int ks = 0; ks < 4; ++ks) {
            union { uint4 u; bf16x8 v; } av;
            av.u = w2s[(w * 4 + ks) * 64 + l];
            acc = __builtin_amdgcn_mfma_f32_32x32x16_bf16(av.v, Bf[ks], acc, 0, 0, 0);
        }
        #pragma unroll
        for (int g = 0; g < 4; ++g) {
            int ch0 = w * 32 + 8 * g + 4 * q;
            ushort4 pk;
            pk.x = (unsigned short)f2bf(acc[4*g+0]);
            pk.y = (unsigned short)f2bf(acc[4*g+1]);
            pk.z = (unsigned short)f2bf(acc[4*g+2]);
            pk.w = (unsigned short)f2bf(acc[4*g+3]);
            *(ushort4*)(y2 + (size_t)p * 128 + ch0) = pk;
        }
        #pragma unroll
        for (int r = 0; r < 16; ++r) { s_acc[r] += acc[r]; q_acc[r] += acc[r]*acc[r]; }
    }
    #pragma unroll
    for (int r = 0; r < 16; ++r) {
        float s = s_acc[r], sq = q_acc[r];
        #pragma unroll
        for (int off = 16; off > 0; off >>= 1) {
            s  += __shfl_xor(s, off);
            sq += __shfl_xor(sq, off);
        }
        if ((l & 31) == 0) {
            int ch = w * 32 + (r & 3) + 8 * (r >> 2) + 4 * q;
            atomicAdd(&st2[ch * 16], s);
            atomicAdd(&st2[(128 + ch) * 16], sq);
        }
    }
}

// ---- Kernel 4 (MFMA): y3F = frag-layout(bf16(y2f @ W3)) at slot order ----
__global__ __launch_bounds__(256, 2) void k_lin3(
    const unsigned short* __restrict__ y2f, const uint4* __restrict__ W3F,
    const unsigned* __restrict__ inv, uint4* __restrict__ y3F,
    float* __restrict__ st3)
{
    __shared__ uint4 w3s[4096];        // 64 KB
    const int tid = threadIdx.x, l = tid & 63, w = tid >> 6;
    #pragma unroll
    for (int r = 0; r < 16; ++r) w3s[r * 256 + tid] = W3F[r * 256 + tid];
    __syncthreads();
    const int n = l & 31, q = l >> 5;
    float s_acc[32], q_acc[32];
    #pragma unroll
    for (int r = 0; r < 32; ++r) { s_acc[r] = 0.f; q_acc[r] = 0.f; }

    for (int t = 0; t < 8; ++t) {
        const int p = (blockIdx.x * 8 + t) * 32 + n;
        const unsigned short* yrow = y2f + (size_t)p * 128 + q * 8;
        bf16x8 Bf[8];
        #pragma unroll
        for (int ks = 0; ks < 8; ++ks) {
            union { uint4 u; bf16x8 v; } bv;
            bv.u = *(const uint4*)(yrow + ks * 16);
            Bf[ks] = bv.v;
        }
        f32x16 acc[2];
        #pragma unroll
        for (int i = 0; i < 2; ++i)
            #pragma unroll
            for (int r = 0; r < 16; ++r) acc[i][r] = 0.f;
        #pragma unroll
        for (int ks = 0; ks < 8; ++ks) {
            #pragma unroll
            for (int i = 0; i < 2; ++i) {
                union { uint4 u; bf16x8 v; } av;
                av.u = w3s[((w * 2 + i) * 8 + ks) * 64 + l];
                acc[i] = __builtin_amdgcn_mfma_f32_32x32x16_bf16(av.v, Bf[ks], acc[i], 0, 0, 0);
            }
        }
        #pragma unroll
        for (int i = 0; i < 2; ++i)
            #pragma unroll
            for (int r = 0; r < 16; ++r) {
                s_acc[i*16+r] += acc[i][r];
                q_acc[i*16+r] += acc[i][r] * acc[i][r];
            }
        const unsigned slotn = inv[p];
        const int fb = (int)(slotn >> 5) * 16;       // frag base of tile
        const int li = (int)(slotn & 31) + 32 * q;   // lane in target frag
        #pragma unroll
        for (int i = 0; i < 2; ++i) {
            #pragma unroll
            for (int s = 0; s < 2; ++s) {
                float V[8];
                #pragma unroll
                for (int j = 0; j < 4; ++j) {
                    float tmp = q ? acc[i][8*s + j] : acc[i][8*s + 4 + j];
                    float got = __shfl_xor(tmp, 32);
                    V[j]     = q ? got : acc[i][8*s + j];
                    V[4 + j] = q ? acc[i][8*s + 4 + j] : got;
                }
                uint4 pk;
                pk.x = f2bf(V[0]) | (f2bf(V[1]) << 16);
                pk.y = f2bf(V[2]) | (f2bf(V[3]) << 16);
                pk.z = f2bf(V[4]) | (f2bf(V[5]) << 16);
                pk.w = f2bf(V[6]) | (f2bf(V[7]) << 16);
                y3F[(size_t)(fb + w * 4 + 2 * i + s) * 64 + li] = pk;
            }
        }
    }
    #pragma unroll
    for (int i = 0; i < 2; ++i)
        #pragma unroll
        for (int r = 0; r < 16; ++r) {
            float s = s_acc[i*16+r], sq = q_acc[i*16+r];
            #pragma unroll
            for (int off = 16; off > 0; off >>= 1) {
                s  += __shfl_xor(s, off);
                sq += __shfl_xor(sq, off);
            }
            if ((l & 31) == 0) {
                int ch = (w * 2 + i) * 32 + (r & 3) + 8 * (r >> 2) + 4 * q;
                atomicAdd(&st3[ch * 16], s);
                atomicAdd(&st3[(256 + ch) * 16], sq);
            }
        }
}

// ---- Kernel 5 (MFMA): COALESCED frag-X GEMM + register segmented max ----
// Round-16 body verbatim: 1024 blocks (groups of 4 + 1 overlap), Xf from
// slot-ordered y3F (coalesced), sub loop unroll 1, carry in explicit LDS,
// store loop fully unrolled (compile-time v[m], SGPR-bit guards).
__global__ __launch_bounds__(256, 2) void k_smax(
    const uint4* __restrict__ y3F, const uint4* __restrict__ W4F,
    const unsigned* __restrict__ pidf, const unsigned* __restrict__ send,
    const unsigned* __restrict__ skey, unsigned short* __restrict__ pooled)
{
    __shared__ float s0c_s[4 * 256];   // 4 KB carry; [sub*256+tid], no sync
    const int tid = threadIdx.x, l = tid & 63, w = tid >> 6;
    const int wg = blockIdx.x;         // 0..1023
    const int q = l >> 5;

    #pragma unroll
    for (int sub = 0; sub < 4; ++sub) s0c_s[sub * 256 + tid] = -3.4e38f;

    #pragma unroll 1
    for (int t = 4; t >= 0; --t) {     // t=4 is carry-only overlap window
        const int p0 = (wg * 4 + t) * 32;
        const int pos = p0 + (l & 31);
        const int sp = pos < P_TOT ? pos : P_TOT - 1;
        const unsigned pf = pidf[sp];
        const unsigned e_l = send[sp];
        const unsigned key_l = skey[sp];
        const unsigned cmask =
            (unsigned)__ballot((unsigned)(pos + 1) < e_l);
        const unsigned fmask =
            (unsigned)__ballot((pf & 0x80000000u) != 0u);
        // X fragments: coalesced (slot-ordered frag layout), reused 4x
        const int tt = (wg * 4 + t) < 4096 ? (wg * 4 + t) : 4095;
        const uint4* xb = y3F + (size_t)tt * 16 * 64;
        uint4 Xf[16];
        #pragma unroll
        for (int ks = 0; ks < 16; ++ks)
            Xf[ks] = xb[ks * 64 + l];

        #pragma unroll 1
        for (int sub = 0; sub < 4; ++sub) {
            const int nt = sub * 4 + w;          // channel tile (32 ch)
            f32x16 acc;
            #pragma unroll
            for (int r = 0; r < 16; ++r) acc[r] = 0.f;
            #pragma unroll
            for (int ks = 0; ks < 16; ++ks) {
                union { uint4 u; bf16x8 v; } xv, wv;
                xv.u = Xf[ks];
                wv.u = W4F[(size_t)(nt * 16 + ks) * 64 + l];
                // A=X (M=points), B=W4 (N=channels) -> C: lane=ch, reg=point
                acc = __builtin_amdgcn_mfma_f32_32x32x16_bf16(xv.v, wv.v, acc, 0, 0, 0);
            }
            // half-exchange: v[point 0..31] per lane (lane = channel)
            float v[32];
            #pragma unroll
            for (int r = 0; r < 16; ++r) {
                int base = (r & 3) + 8 * (r >> 2);
                float o = __shfl_xor(acc[r], 32);
                v[base]     = q ? o : acc[r];
                v[base + 4] = q ? acc[r] : o;
            }
            // segmented suffix-max, SGPR-bit conditions, compile-time indices
            if ((cmask >> 31) & 1)
                v[31] = fmaxf(v[31], s0c_s[sub * 256 + tid]);
            #pragma unroll
            for (int m = 30; m >= 0; --m)
                if ((cmask >> m) & 1) v[m] = fmaxf(v[m], v[m + 1]);
            s0c_s[sub * 256 + tid] = v[0];
            // stores: fully unrolled, wave-uniform bit guard, v[m] compile-time
            if (t < 4) {
                #pragma unroll
                for (int m = 0; m < 32; ++m) {
                    if ((fmask >> m) & 1) {
                        unsigned km = (unsigned)
                            __builtin_amdgcn_readlane((int)key_l, m);
                        if ((m >> 4) == q)
                            pooled[(size_t)km * 512 + nt * 32 + (l & 31)] =
                                (unsigned short)f2bf(v[m]);
                    }
                }
            }
        }
    }
}

// ---- Kernel 6 (MFMA): comp = relu(pooled @ Wc); transpose to [B,CMP,H,W] ----
__global__ __launch_bounds__(256, 4) void k_out(
    const unsigned short* __restrict__ pooled, const unsigned* __restrict__ counts,
    const uint4* __restrict__ WcF, float* __restrict__ out)
{
    __shared__ uint4 wcs[2048];        // 32 KB: full WcF
    const int tid = threadIdx.x, l = tid & 63, w = tid >> 6;
    const int sbase = blockIdx.x * 128;
    #pragma unroll
    for (int r = 0; r < 8; ++r) wcs[r * 256 + tid] = WcF[r * 256 + tid];
    __syncthreads();
    const int n = l & 31, q = l >> 5;
    const int s = sbase + w * 32 + n;
    const bool occ = counts[s] > 0;
    // unoccupied voxels read the (hot) line-0 row instead of cold poison
    const unsigned short* prow =
        pooled + (occ ? (size_t)s * 512 : (size_t)0) + q * 8;
    f32x16 acc;
    #pragma unroll
    for (int r = 0; r < 16; ++r) acc[r] = 0.f;

    for (int ks = 0; ks < 32; ++ks) {
        union { uint4 u; bf16x8 v; } bv;
        bv.u = *(const uint4*)(prow + ks * 16);   // raw bf16 IS the B frag
        union { uint4 u; bf16x8 v; } av;
        av.u = wcs[ks * 64 + l];
        acc = __builtin_amdgcn_mfma_f32_32x32x16_bf16(av.v, bv.v, acc, 0, 0, 0);
    }
    const int b = s >> 16, hw = s & 65535;
    #pragma unroll
    for (int r = 0; r < 16; ++r) {
        int ch = (r & 3) + 8 * (r >> 2) + 4 * q;
        float x = occ ? fmaxf(acc[r], 0.f) : 0.f;
        out[(size_t)b * (32 * HWSZ) + (size_t)ch * HWSZ + hw] = x;
    }
}

extern "C" void kernel_launch(void* const* d_in, const int* in_sizes, int n_in,
                              void* d_out, int out_size, void* d_ws, size_t ws_size,
                              hipStream_t stream) {
    const float* pt = (const float*)d_in[0];
    const float* g0 = (const float*)d_in[1];
    const float* b0 = (const float*)d_in[2];
    const float* W1 = (const float*)d_in[3];
    const float* g1 = (const float*)d_in[4];
    const float* b1 = (const float*)d_in[5];
    const float* W2 = (const float*)d_in[6];
    const float* g2 = (const float*)d_in[7];
    const float* b2 = (const float*)d_in[8];
    const float* W3 = (const float*)d_in[9];
    const float* g3 = (const float*)d_in[10];
    const float* b3 = (const float*)d_in[11];
    const float* W4 = (const float*)d_in[12];
    const float* Wc = (const float*)d_in[13];
    const int*   xy = (const int*)d_in[14];
    float* out = (float*)d_out;

    char* ws = (char*)d_ws;
    uint4*          y3F    = (uint4*)(ws + OFF_Y3);
    unsigned short* y3u    = (unsigned short*)(ws + OFF_Y3);
    unsigned short* y1     = (unsigned short*)(ws + OFF_Y1);
    unsigned short* y2     = (unsigned short*)(ws + OFF_Y2);
    unsigned short* pool16 = (unsigned short*)(ws + OFF_POOL);
    unsigned*       counts = (unsigned*)(ws + OFF_CNT);
    float*          st     = (float*)(ws + OFF_ST);
    unsigned*       offs   = (unsigned*)(ws + OFF_OFFS);
    unsigned*       cur    = (unsigned*)(ws + OFF_CUR);
    unsigned*       bsum   = (unsigned*)(ws + OFF_BSUM);
    unsigned*       pidf   = (unsigned*)(ws + OFF_PIDF);
    unsigned*       send   = (unsigned*)(ws + OFF_SEND);
    unsigned*       skey   = (unsigned*)(ws + OFF_SKEY);
    unsigned*       inv    = (unsigned*)(ws + OFF_INV);
    uint4* W3F = (uint4*)(ws + OFF_W3F);
    uint4* W4F = (uint4*)(ws + OFF_W4F);
    uint4* WcF = (uint4*)(ws + OFF_WCF);
    uint4* W2F = (uint4*)(ws + OFF_W2F);
    float* scsh = (float*)(ws + OFF_SCSH);
    float* sc2 = scsh;       float* sh2 = scsh + 128;
    float* sc3 = scsh + 256; float* sh3 = scsh + 512;
    // padded stats: one 64B line per entry (entry i at st[i*16])
    float* st0 = st;            // 16 entries
    float* st1 = st + 256;      // 128 entries
    float* st2 = st + 2304;     // 256 entries
    float* st3 = st + 6400;     // 512 entries

    // zero counts+stats+offs+cur in one contiguous pass (1638400 B)
    k_zero<<<400, 256, 0, stream>>>((uint4*)(ws + OFF_CNT), 102400);
    // weights -> bf16 frag layout
    k_prepw<<<92, 256, 0, stream>>>(W2, W3, W4, Wc, W2F, W3F, W4F, WcF);

    k_stats0<<<512, 256, 0, stream>>>(pt, xy, st0, counts);
    // counting sort: counts -> offs -> slot fill (+ inverse perm)
    k_scan1<<<512, 256, 0, stream>>>(counts, bsum);
    k_scan2<<<1,   256, 0, stream>>>(bsum, bsum + 512);
    k_scan3<<<512, 256, 0, stream>>>(counts, bsum + 512, offs);
    k_fill<<<512, 256, 0, stream>>>(xy, offs, counts, cur, pidf, send, skey, inv);

    k_lin1<<<512, 256, 0, stream>>>(pt, g0, b0, W1, st0, y1, st1);
    k_lin2<<<512, 256, 0, stream>>>(y1, g1, b1, W2F, st1, y2, st2);
    k_bnprep<<<1, 256, 0, stream>>>(st2, g2, b2, sc2, sh2, 128);
    k_fold<<<8192, 256, 0, stream>>>(y2, sc2, sh2, 128, 2097152);
    k_lin3<<<512, 256, 0, stream>>>(y2, W3F, inv, y3F, st3);
    k_bnprep<<<1, 256, 0, stream>>>(st3, g3, b3, sc3, sh3, 256);
    k_foldf<<<16384, 256, 0, stream>>>(y3u, sc3, sh3, 4194304);

    k_smax<<<1024, 256, 0, stream>>>(y3F, W4F, pidf, send, skey, pool16);
    k_out<<<S_TOT / 128, 256, 0, stream>>>(pool16, counts, WcF, out);
}